// Round 7
// baseline (431.358 us; speedup 1.0000x reference)
//
#include <hip/hip_runtime.h>
#include <hip/hip_bf16.h>

#define NN 20000
#define NE 160000
#define EF (NE + NN)          // edges + self loops
#define DD 128
#define HH 4
#define NPA (NN * DD)                       // pack_a elements
#define NPW (1024 * 128 + 1024)             // pack_w elements (W2T + bias2)
#define DEGB ((NE + 255) / 256)             // deg blocks in fused deg+pack
#define PACKB ((NPA + NPW + 255) / 256)     // pack blocks
#define COMPB 512                           // compose blocks (1024*128 / 256)
#define NBLK 40                             // scan blocks (512 nodes each)

typedef unsigned short u16;
typedef unsigned int u32;

using short8  = __attribute__((ext_vector_type(8))) short;
using ushort8 = __attribute__((ext_vector_type(8))) unsigned short;
using float4v = __attribute__((ext_vector_type(4))) float;
using f32x2   = __attribute__((ext_vector_type(2))) float;

__device__ __forceinline__ float bf2f(u16 u) {
    union { u32 i; float f; } c;
    c.i = ((u32)u) << 16;
    return c.f;
}
// round-to-nearest-even fp32 -> bf16 bits (finite inputs)
__device__ __forceinline__ u16 f2bf(float f) {
    union { float f; u32 u; } c;
    c.f = f;
    u32 u = c.u;
    u32 r = (u + 0x7fffu + ((u >> 16) & 1u)) >> 16;
    return (u16)r;
}

// DPP-based add of lane (per 16-lane row): v += dpp(v). VALU-only, no LDS pipe.
template<int CTRL>
__device__ __forceinline__ float dpp_add(float v) {
    int t = __builtin_amdgcn_update_dpp(0, __builtin_bit_cast(int, v),
                                        CTRL, 0xf, 0xf, true);
    return v + __builtin_bit_cast(float, t);
}

// async global->LDS, 16B per lane. LDS dest = wave-uniform base + lane*16.
__device__ __forceinline__ void gld16(const void* g, void* l) {
    __builtin_amdgcn_global_load_lds(
        (const __attribute__((address_space(1))) unsigned int*)g,
        (__attribute__((address_space(3))) unsigned int*)l,
        16, 0, 0);
}

// ---------- utility ----------

__global__ void k_zero_f(float* __restrict__ p, int n) {
    int i = blockIdx.x * blockDim.x + threadIdx.x;
    if (i < n) p[i] = 0.f;
}

// ---------- fused deg + pack + layer-0 weight compose (block ranges) ----------
// R23: k_compose fused in as a third block range (saves one launch + gap).
// Compose (R22-proven): xl|xr = x@(Wf@W2) + (bf@W2 + b2) -> layer-0 GEMM
// reads packed x directly; mgemm<1,2> dispatch deleted.

__global__ void k_degpack(const int* __restrict__ ei, const float* __restrict__ ea,
                          const float* __restrict__ x,
                          const float* __restrict__ Wl, const float* __restrict__ Wr,
                          const float* __restrict__ bl, const float* __restrict__ br,
                          const float* __restrict__ Wf, const float* __restrict__ bf,
                          int* __restrict__ cnt, float* __restrict__ ea_sum,
                          u16* __restrict__ Axh, u16* __restrict__ Axl,
                          u16* __restrict__ W2Th, u16* __restrict__ W2Tl,
                          u16* __restrict__ WcTh, u16* __restrict__ WcTl,
                          float* __restrict__ bias2, float* __restrict__ biasc) {
    int gb = blockIdx.x;
    if (gb < DEGB) {
        int e = gb * 256 + threadIdx.x;
        if (e >= NE) return;
        int t = ei[NE + e];
        atomicAdd(&cnt[t], 1);
        atomicAdd(&ea_sum[t * 2 + 0], ea[e * 2 + 0]);
        atomicAdd(&ea_sum[t * 2 + 1], ea[e * 2 + 1]);
        return;
    }
    if (gb < DEGB + PACKB) {
        int i = (gb - DEGB) * 256 + threadIdx.x;
        if (i < NPA) {
            float a = x[i];
            u16 h = f2bf(a);
            Axh[i] = h;
            Axl[i] = f2bf(a - bf2f(h));
            return;
        }
        i -= NPA;
        if (i < 1024 * 128) {
            int n = i >> 7, k = i & 127;
            float w = (n < 512) ? Wl[k * 512 + n] : Wr[k * 512 + (n - 512)];
            u16 h = f2bf(w);
            W2Th[n * 128 + k] = h;
            W2Tl[n * 128 + k] = f2bf(w - bf2f(h));
        } else if (i < NPW) {
            int n = i - 1024 * 128;
            bias2[n] = (n < 512) ? bl[n] : br[n - 512];
        }
        return;
    }
    // compose range
    int idx = (gb - DEGB - PACKB) * 256 + threadIdx.x;   // 512 x 256 = 131072
    int n = idx >> 7, f = idx & 127;                     // n wave-uniform
    const float* col = (n < 512) ? &Wl[n] : &Wr[n - 512];
    float s = 0.f;
    #pragma unroll 4
    for (int d = 0; d < 128; ++d)
        s = fmaf(Wf[f * 128 + d], col[d * 512], s);
    u16 h = f2bf(s);
    WcTh[n * 128 + f] = h;
    WcTl[n * 128 + f] = f2bf(s - bf2f(h));
    if (f == 0) {
        float b = (n < 512) ? bl[n] : br[n - 512];
        for (int d = 0; d < 128; ++d)
            b = fmaf(bf[d], col[d * 512], b);
        biasc[n] = b;
    }
}

// ---------- parallel scan (R12/R16-verified pair) ----------

__global__ __launch_bounds__(512) void k_scan_a(const int* __restrict__ cnt,
                                                int* __restrict__ rowptr,
                                                int* __restrict__ bsum) {
    __shared__ int ws[8];
    int tid = threadIdx.x;
    int i = blockIdx.x * 512 + tid;
    int l = tid & 63, w = tid >> 6;
    int v = (i < NN) ? (cnt[i] + 1) : 0;
    #pragma unroll
    for (int off = 1; off < 64; off <<= 1) {
        int u = __shfl_up(v, off, 64);
        if (l >= off) v += u;
    }
    if (l == 63) ws[w] = v;
    __syncthreads();
    if (w == 0) {
        int s = (l < 8) ? ws[l] : 0;
        #pragma unroll
        for (int off = 1; off < 8; off <<= 1) {
            int u = __shfl_up(s, off, 64);
            if (l >= off) s += u;
        }
        if (l < 8) ws[l] = s;    // inclusive wave sums
    }
    __syncthreads();
    v += (w > 0) ? ws[w - 1] : 0;
    if (i < NN) rowptr[i + 1] = v;   // block-local inclusive
    if (tid == 511) bsum[blockIdx.x] = v;
}

__global__ void k_scan_c(int* __restrict__ rowptr, const int* __restrict__ bsum) {
    int l = threadIdx.x & 63;
    int v = (l < NBLK) ? bsum[l] : 0;
    #pragma unroll
    for (int off = 1; off < 64; off <<= 1) {
        int u = __shfl_up(v, off, 64);
        if (l >= off) v += u;
    }
    int i = blockIdx.x * blockDim.x + threadIdx.x;
    int j = i >> 9;
    int off = (j > 0) ? __shfl(v, j - 1, 64) : 0;
    if (i < NN) rowptr[i + 1] += off;
    if (i == 0) rowptr[0] = 0;
}

// ---------- fused fill + self-loop ----------

__global__ void k_fill(const int* __restrict__ ei, const float* __restrict__ ea,
                       const int* __restrict__ rowptr, int* __restrict__ fillc,
                       const int* __restrict__ cnt, const float* __restrict__ ea_sum,
                       int* __restrict__ srcs,
                       float* __restrict__ fa0, float* __restrict__ fa1) {
    int e = blockIdx.x * blockDim.x + threadIdx.x;
    if (e < NE) {
        int s = ei[e], t = ei[NE + e];
        int pos = atomicAdd(&fillc[t], 1);
        int slot = rowptr[t] + pos;
        srcs[slot] = s;
        fa0[slot] = ea[e * 2];
        fa1[slot] = ea[e * 2 + 1];
    } else if (e < NE + NN) {
        int n = e - NE;
        int slot = rowptr[n + 1] - 1;   // self-loop is last slot
        srcs[slot] = n;
        float c = fmaxf((float)cnt[n], 1.f);
        fa0[slot] = ea_sum[n * 2 + 0] / c;
        fa1[slot] = ea_sum[n * 2 + 1] / c;
    }
}

// ---------- split-bf16 MFMA GEMM: 128x64-band, 8-wave ----------
// R23: staging-mechanism variants (R3/R4/R5) all failed; the untried axis is
// COMPUTE-PER-BARRIER. M-tile doubled to 128 (8 waves, wm 0..3); per-wave
// inner loop / swizzle / epilogue bit-identical to the R2-proven code. Per
// block: 4 staging drains instead of 8, 384 MFMA per drain; B-staging bytes
// per output halved; LDS 64 KB -> 2 blocks/CU = 16 waves (up from 12).

template<int NB>
__global__ __launch_bounds__(512, 4) void k_mgemm(
        const u16* __restrict__ Ahg, const u16* __restrict__ Alg,
        const u16* __restrict__ BTh, const u16* __restrict__ BTl,
        const float* __restrict__ bias, float* __restrict__ C1,
        u16* __restrict__ C2b, int M) {
    __shared__ u16 sAh[128 * 128], sBh[64 * 128], sBl[64 * 128];
    int m0 = blockIdx.y * 128;
    int t = threadIdx.x;            // 0..511
    int lane = t & 63;
    int wm = (t >> 6) & 3;          // 4 m-positions
    int wn = t >> 8;                // 2 n-positions
    int fm = lane & 15;
    int q8 = (lane >> 4) * 8;

    // preload A-lo fragments into registers (8 x 16B per lane).
    // OOB rows (tail tile) read garbage within the workspace; their C rows
    // are masked at store (MFMA row r depends only on A row r).
    short8 fal[4][2];
    #pragma unroll
    for (int i = 0; i < 2; ++i) {
        int gm = m0 + wm * 32 + i * 16 + fm;
        if (gm > M - 1) gm = M - 1;
        const u16* p = Alg + (size_t)gm * 128 + q8;
        #pragma unroll
        for (int kk = 0; kk < 4; ++kk)
            fal[kk][i] = *(const short8*)(p + kk * 32);
    }

    // stage A-hi once via global_load_lds: linear LDS chunk = lane slot,
    // global source pre-swizzled (chunk ch' holds logical chunk ch'^(row&15)).
    // 128 rows x 16 chunks = 2048 chunks, 512 threads -> 4 iters.
    #pragma unroll
    for (int i = 0; i < 4; ++i) {
        int cb = (t & 448) + 512 * i;   // wave-uniform chunk base
        int c = cb + lane;
        int row = c >> 4, ch = c & 15;
        int gm = m0 + row;
        if (gm >= M) gm = M - 1;        // clamp: OOB rows finite, never stored
        gld16(&Ahg[(size_t)gm * 128 + ((ch ^ (row & 15)) << 3)], &sAh[cb * 8]);
    }

    int cq = q8 >> 3;   // quarter (0..3)

    for (int bb = 0; bb < NB; ++bb) {
        int n0 = (blockIdx.x * NB + bb) * 64;
        __syncthreads();   // protect sBh/sBl overwrite (covers sAh on bb=0)
        // stage B: 64 rows x 16 chunks = 1024 chunks, 512 threads -> 2 iters
        #pragma unroll
        for (int i = 0; i < 2; ++i) {
            int cb = (t & 448) + 512 * i;
            int c = cb + lane;
            int row = c >> 4, ch = c & 15;
            size_t gofs = (size_t)(n0 + row) * 128 + ((ch ^ (row & 15)) << 3);
            gld16(&BTh[gofs], &sBh[cb * 8]);
            gld16(&BTl[gofs], &sBl[cb * 8]);
        }
        __syncthreads();   // vmcnt(0) drained by compiler before barrier

        float4v zz = {0.f, 0.f, 0.f, 0.f};
        float4v acc[2][2];
        acc[0][0] = zz; acc[0][1] = zz; acc[1][0] = zz; acc[1][1] = zz;

        #pragma unroll
        for (int k0 = 0; k0 < 128; k0 += 32) {
            int cl = (k0 >> 3) + cq;        // logical chunk
            int sw = (cl ^ fm) << 3;        // swizzled chunk offset
            short8 fah[2], fbh[2], fbl[2];
            #pragma unroll
            for (int i = 0; i < 2; ++i) {
                int mr = wm * 32 + i * 16 + fm;
                fah[i] = *(const short8*)&sAh[mr * 128 + sw];
                int nr = wn * 32 + i * 16 + fm;
                fbh[i] = *(const short8*)&sBh[nr * 128 + sw];
                fbl[i] = *(const short8*)&sBl[nr * 128 + sw];
            }
            #pragma unroll
            for (int i = 0; i < 2; ++i)
                #pragma unroll
                for (int j = 0; j < 2; ++j) {
                    acc[i][j] = __builtin_amdgcn_mfma_f32_16x16x32_bf16(fah[i], fbh[j], acc[i][j], 0, 0, 0);
                    acc[i][j] = __builtin_amdgcn_mfma_f32_16x16x32_bf16(fah[i], fbl[j], acc[i][j], 0, 0, 0);
                    acc[i][j] = __builtin_amdgcn_mfma_f32_16x16x32_bf16(fal[k0 >> 5][i], fbh[j], acc[i][j], 0, 0, 0);
                }
        }

        // epilogue: C/D layout col=lane&15, row=(lane>>4)*4+reg  [m89]
        #pragma unroll
        for (int i = 0; i < 2; ++i) {
            #pragma unroll
            for (int j = 0; j < 2; ++j) {
                int gn = n0 + wn * 32 + j * 16 + fm;
                float bv = bias[gn];
                #pragma unroll
                for (int r = 0; r < 4; ++r) {
                    int gm = m0 + wm * 32 + i * 16 + (lane >> 4) * 4 + r;
                    if (gm < M) {
                        float v = acc[i][j][r] + bv;
                        if (n0 < 512) {
                            C1[gm * 512 + gn] = v;               // xl fp32
                        } else {
                            C2b[gm * 512 + gn - 512] = f2bf(v);  // xr bf16
                        }
                    }
                }
            }
        }
    }
}

// ---------- fused per-node GATv2: one node per 128-thread block ----------
// R18-R22: k_gat is at the scattered-fill BW floor (FETCH pinned ~180 MB @
// ~3.6 TB/s L2-fill; VALU ~38%; unroll-4 probe moved <2%). Unchanged.

__global__ __launch_bounds__(128) void k_gat(
        const int* __restrict__ rowptr, const int* __restrict__ srcs,
        const float* __restrict__ fa0, const float* __restrict__ fa1,
        const float* __restrict__ xl, const u16* __restrict__ xr,
        const float* __restrict__ We, const float* __restrict__ att,
        const float* __restrict__ bias_out,
        u16* __restrict__ Oh, u16* __restrict__ Ol,
        float* __restrict__ outp, int last) {
    __shared__ float sacc[512];
    __shared__ float sden[4];
    int half = threadIdx.x >> 6;     // 0: even edges + epilogue, 1: odd edges
    int n = blockIdx.x;
    int l = threadIdx.x & 63;
    int d0 = l * 8;

    // per-node constants as packed pairs
    f32x2 xr2[4], we0p[4], we1p[4], at6p[4], at4p[4];
    {
        ushort8 u = *reinterpret_cast<const ushort8*>(&xr[(size_t)n * 512 + d0]);
        #pragma unroll
        for (int k = 0; k < 4; ++k) {
            f32x2 t; t.x = bf2f(u[2 * k]); t.y = bf2f(u[2 * k + 1]);
            xr2[k] = t;
        }
        const f32x2* w0 = reinterpret_cast<const f32x2*>(&We[d0]);
        const f32x2* w1 = reinterpret_cast<const f32x2*>(&We[512 + d0]);
        const f32x2* av = reinterpret_cast<const f32x2*>(&att[d0]);
        #pragma unroll
        for (int k = 0; k < 4; ++k) {
            we0p[k] = w0[k];
            we1p[k] = w1[k];
            f32x2 a = av[k];
            at6p[k] = a * 0.6f;
            at4p[k] = a * 0.4f;
        }
    }

    int b0 = rowptr[n], b1 = rowptr[n + 1];
    int nit = (b1 - b0 - half + 1) >> 1;   // edges of my parity (deg>=1 always)

    // preload my half's edge metadata: lane l owns edge b0 + half + 2*l
    int sv = 0, f0i = 0, f1i = 0;
    {
        int me = b0 + half + 2 * l;
        if (l < nit) {
            sv  = srcs[me];
            f0i = __builtin_bit_cast(int, fa0[me]);
            f1i = __builtin_bit_cast(int, fa1[me]);
        }
    }

    f32x2 acc2[4];
    acc2[0] = f32x2{0.f, 0.f}; acc2[1] = f32x2{0.f, 0.f};
    acc2[2] = f32x2{0.f, 0.f}; acc2[3] = f32x2{0.f, 0.f};
    float den = 0.f;

    auto body = [&](float4 A, float4 B, float f0, float f1) {
        f32x2 f0p; f0p.x = f0; f0p.y = f0;
        f32x2 f1p; f1p.x = f1; f1p.y = f1;
        f32x2 xv2[4];
        xv2[0].x = A.x; xv2[0].y = A.y;
        xv2[1].x = A.z; xv2[1].y = A.w;
        xv2[2].x = B.x; xv2[2].y = B.y;
        xv2[3].x = B.z; xv2[3].y = B.w;
        f32x2 p2 = {0.f, 0.f};
        #pragma unroll
        for (int k = 0; k < 4; ++k) {
            f32x2 t = __builtin_elementwise_fma(f0p, we0p[k], xr2[k]);
            t = __builtin_elementwise_fma(f1p, we1p[k], t);
            f32x2 v2 = xv2[k] + t;
            f32x2 a2 = __builtin_elementwise_abs(v2);
            p2 = __builtin_elementwise_fma(at6p[k], v2, p2);
            p2 = __builtin_elementwise_fma(at4p[k], a2, p2);
        }
        float p = p2.x + p2.y;
        p = dpp_add<0xB1>(p);    // quad_perm xor1
        p = dpp_add<0x4E>(p);    // quad_perm xor2
        p = dpp_add<0x124>(p);   // row_ror:4
        p = dpp_add<0x128>(p);   // row_ror:8 -> full 16-lane (per-head) sum
        float wt = __expf(p);    // |p| small by construction
        den += wt;
        f32x2 wtp; wtp.x = wt; wtp.y = wt;
        #pragma unroll
        for (int k = 0; k < 4; ++k)
            acc2[k] = __builtin_elementwise_fma(wtp, xv2[k], acc2[k]);
    };

    int nfast = nit < 64 ? nit : 64;
    #pragma unroll 4
    for (int it = 0; it < nfast; ++it) {
        int   s  = __builtin_amdgcn_readlane(sv, it);
        float f0 = __builtin_bit_cast(float, __builtin_amdgcn_readlane(f0i, it));
        float f1 = __builtin_bit_cast(float, __builtin_amdgcn_readlane(f1i, it));
        const float* xp = &xl[(size_t)s * 512 + d0];
        float4 A = *reinterpret_cast<const float4*>(xp);
        float4 B = *reinterpret_cast<const float4*>(xp + 4);
        body(A, B, f0, f1);
    }
    // safety tail for deg > 129 (unreachable for this input distribution)
    for (int e = b0 + half + 128; e < b1; e += 2) {
        int s = srcs[e];
        const float* xp = &xl[(size_t)s * 512 + d0];
        float4 A = *reinterpret_cast<const float4*>(xp);
        float4 B = *reinterpret_cast<const float4*>(xp + 4);
        body(A, B, fa0[e], fa1[e]);
    }

    // pair merge: odd wave publishes, even wave combines
    if (half == 1) {
        *reinterpret_cast<float4*>(&sacc[d0]) =
            make_float4(acc2[0].x, acc2[0].y, acc2[1].x, acc2[1].y);
        *reinterpret_cast<float4*>(&sacc[d0 + 4]) =
            make_float4(acc2[2].x, acc2[2].y, acc2[3].x, acc2[3].y);
        if ((l & 15) == 0) sden[l >> 4] = den;
    }
    __syncthreads();
    if (half == 1) return;
    float acc[8] = {acc2[0].x, acc2[0].y, acc2[1].x, acc2[1].y,
                    acc2[2].x, acc2[2].y, acc2[3].x, acc2[3].y};
    #pragma unroll
    for (int k = 0; k < 8; ++k) acc[k] += sacc[d0 + k];
    den += sden[l >> 4];
    // per-head normalize (den identical across the 16 lanes of a head)
    float inv = 1.f / den;
    float val[8];
    #pragma unroll
    for (int k = 0; k < 8; ++k) {
        float v = acc[k] * inv;
        v += __shfl_xor(v, 16, 64);   // sum heads
        v += __shfl_xor(v, 32, 64);
        val[k] = v;
    }
    if (l < 16) {
        #pragma unroll
        for (int k = 0; k < 8; ++k) {
            float v = val[k] * 0.25f + bias_out[d0 + k];
            v = v > 0.f ? v : 0.01f * v;
            val[k] = v;
        }
        if (last) {
            #pragma unroll
            for (int k = 0; k < 8; ++k) outp[n * 128 + d0 + k] = val[k];
        } else {
            #pragma unroll
            for (int k = 0; k < 8; ++k) {
                u16 hv = f2bf(val[k]);
                Oh[n * 128 + d0 + k] = hv;
                Ol[n * 128 + d0 + k] = f2bf(val[k] - bf2f(hv));
            }
        }
    }
}

// ---------- launch ----------

extern "C" void kernel_launch(void* const* d_in, const int* in_sizes, int n_in,
                              void* d_out, int out_size, void* d_ws, size_t ws_size,
                              hipStream_t stream) {
    size_t o = 0;
    auto alloc = [&](size_t bytes) { size_t cur = o; o += (bytes + 255) & ~(size_t)255; return cur; };
    size_t off_cnt    = alloc((size_t)NN * 4);
    size_t off_fillc  = alloc((size_t)NN * 4);
    size_t off_easum  = alloc((size_t)NN * 2 * 4);
    size_t off_rowptr = alloc((size_t)(NN + 1) * 4);
    size_t off_bsum   = alloc((size_t)NBLK * 4);
    size_t off_srcs   = alloc((size_t)EF * 4);
    size_t off_fa0    = alloc((size_t)EF * 4);
    size_t off_fa1    = alloc((size_t)EF * 4);
    size_t off_axh    = alloc((size_t)NN * DD * 2);
    size_t off_axl    = alloc((size_t)NN * DD * 2);
    size_t off_ah     = alloc((size_t)NN * DD * 2);
    size_t off_al     = alloc((size_t)NN * DD * 2);
    size_t off_xl     = alloc((size_t)NN * 512 * 4);
    size_t off_xr     = alloc((size_t)NN * 512 * 2);   // bf16
    size_t off_w2th   = alloc((size_t)1024 * 128 * 2);
    size_t off_w2tl   = alloc((size_t)1024 * 128 * 2);
    size_t off_wcth   = alloc((size_t)1024 * 128 * 2);
    size_t off_wctl   = alloc((size_t)1024 * 128 * 2);
    size_t off_bias2  = alloc((size_t)1024 * 4);
    size_t off_biasc  = alloc((size_t)1024 * 4);
    size_t need = o;

    bool ok = (n_in == 12) && d_ws != nullptr && ws_size >= need
           && out_size == NN * DD
           && in_sizes[0] == NN * DD && in_sizes[1] == 2 * NE
           && in_sizes[2] == NE * 2 && in_sizes[3] == 128 * 128
           && in_sizes[5] == 128 * 512 && in_sizes[9] == 2 * 512
           && in_sizes[10] == 4 * 128 && in_sizes[11] == 128;
    if (!ok) {
        k_zero_f<<<(NN * DD + 255) / 256, 256, 0, stream>>>((float*)d_out, NN * DD);
        return;
    }

    const float* x        = (const float*)d_in[0];
    const int*   ei       = (const int*)d_in[1];
    const float* ea       = (const float*)d_in[2];
    const float* Wf       = (const float*)d_in[3];
    const float* bf       = (const float*)d_in[4];
    const float* Wl       = (const float*)d_in[5];
    const float* bl       = (const float*)d_in[6];
    const float* Wr       = (const float*)d_in[7];
    const float* br       = (const float*)d_in[8];
    const float* We       = (const float*)d_in[9];
    const float* att      = (const float*)d_in[10];
    const float* bias_out = (const float*)d_in[11];

    char* base = (char*)d_ws;
    int*   cnt    = (int*)(base + off_cnt);
    int*   fillc  = (int*)(base + off_fillc);
    float* ea_sum = (float*)(base + off_easum);
    int*   rowptr = (int*)(base + off_rowptr);
    int*   bsum   = (int*)(base + off_bsum);
    int*   srcs   = (int*)(base + off_srcs);
    float* fa0    = (float*)(base + off_fa0);
    float* fa1    = (float*)(base + off_fa1);
    u16*   Axh    = (u16*)(base + off_axh);
    u16*   Axl    = (u16*)(base + off_axl);
    u16*   Ah     = (u16*)(base + off_ah);
    u16*   Al     = (u16*)(base + off_al);
    float* xl     = (float*)(base + off_xl);
    u16*   xr     = (u16*)(base + off_xr);
    u16*   W2Th   = (u16*)(base + off_w2th);
    u16*   W2Tl   = (u16*)(base + off_w2tl);
    u16*   WcTh   = (u16*)(base + off_wcth);
    u16*   WcTl   = (u16*)(base + off_wctl);
    float* bias2  = (float*)(base + off_bias2);
    float* biasc  = (float*)(base + off_biasc);

    // zero cnt/fillc/ea_sum (contiguous region) without a kernel launch
    size_t zero_bytes = off_easum + (size_t)NN * 2 * 4 - off_cnt;
    hipMemsetAsync(cnt, 0, zero_bytes, stream);

    k_degpack<<<DEGB + PACKB + COMPB, 256, 0, stream>>>(
        ei, ea, x, Wl, Wr, bl, br, Wf, bf, cnt, ea_sum, Axh, Axl,
        W2Th, W2Tl, WcTh, WcTl, bias2, biasc);
    k_scan_a<<<NBLK, 512, 0, stream>>>(cnt, rowptr, bsum);
    k_scan_c<<<(NN + 255) / 256, 256, 0, stream>>>(rowptr, bsum);
    k_fill<<<(NE + NN + 255) / 256, 256, 0, stream>>>(ei, ea, rowptr, fillc,
                                                      cnt, ea_sum, srcs, fa0, fa1);

    const int MT = (NN + 127) / 128;   // 157
    for (int layer = 0; layer < 3; ++layer) {
        const u16*   Ahp = (layer == 0) ? Axh  : Ah;
        const u16*   Alp = (layer == 0) ? Axl  : Al;
        const u16*   Bhp = (layer == 0) ? WcTh : W2Th;
        const u16*   Blp = (layer == 0) ? WcTl : W2Tl;
        const float* bp  = (layer == 0) ? biasc : bias2;
        k_mgemm<4><<<dim3(4, MT), 512, 0, stream>>>(Ahp, Alp, Bhp, Blp,
                                                    bp, xl, xr, NN);
        int last = (layer == 2);
        k_gat<<<NN, 128, 0, stream>>>(rowptr, srcs, fa0, fa1, xl, xr,
                                      We, att, bias_out, Ah, Al,
                                      (float*)d_out, last);
    }
}

// Round 8
// 390.970 us; speedup vs baseline: 1.1033x; 1.1033x over previous
//
#include <hip/hip_runtime.h>
#include <hip/hip_bf16.h>

#define NN 20000
#define NE 160000
#define EF (NE + NN)          // edges + self loops
#define DD 128
#define HH 4
#define NPA (NN * DD)                       // pack_a elements
#define NPW (1024 * 128 + 128 * 128 + 1024) // pack_w: W2T + WfT32 + bias2
#define DEGB ((NE + 255) / 256)             // deg blocks in fused deg+pack
#define PACKB ((NPA + NPW + 255) / 256)     // pack blocks
#define NBLK 40                             // scan blocks (512 nodes each)

typedef unsigned short u16;
typedef unsigned int u32;

using short8  = __attribute__((ext_vector_type(8))) short;
using ushort8 = __attribute__((ext_vector_type(8))) unsigned short;
using float4v = __attribute__((ext_vector_type(4))) float;
using f32x2   = __attribute__((ext_vector_type(2))) float;

__device__ __forceinline__ float bf2f(u16 u) {
    union { u32 i; float f; } c;
    c.i = ((u32)u) << 16;
    return c.f;
}
// round-to-nearest-even fp32 -> bf16 bits (finite inputs)
__device__ __forceinline__ u16 f2bf(float f) {
    union { float f; u32 u; } c;
    c.f = f;
    u32 u = c.u;
    u32 r = (u + 0x7fffu + ((u >> 16) & 1u)) >> 16;
    return (u16)r;
}

// DPP-based add of lane (per 16-lane row): v += dpp(v). VALU-only, no LDS pipe.
template<int CTRL>
__device__ __forceinline__ float dpp_add(float v) {
    int t = __builtin_amdgcn_update_dpp(0, __builtin_bit_cast(int, v),
                                        CTRL, 0xf, 0xf, true);
    return v + __builtin_bit_cast(float, t);
}

// async global->LDS, 16B per lane. LDS dest = wave-uniform base + lane*16.
__device__ __forceinline__ void gld16(const void* g, void* l) {
    __builtin_amdgcn_global_load_lds(
        (const __attribute__((address_space(1))) unsigned int*)g,
        (__attribute__((address_space(3))) unsigned int*)l,
        16, 0, 0);
}

// ---------- utility ----------

__global__ void k_zero_f(float* __restrict__ p, int n) {
    int i = blockIdx.x * blockDim.x + threadIdx.x;
    if (i < n) p[i] = 0.f;
}

// ---------- fused deg + pack (R6-proven; + WfT32 emit for fast compose) ----------

__global__ void k_degpack(const int* __restrict__ ei, const float* __restrict__ ea,
                          const float* __restrict__ x,
                          const float* __restrict__ Wl, const float* __restrict__ Wr,
                          const float* __restrict__ bl, const float* __restrict__ br,
                          const float* __restrict__ Wf,
                          int* __restrict__ cnt, float* __restrict__ ea_sum,
                          u16* __restrict__ Axh, u16* __restrict__ Axl,
                          u16* __restrict__ W2Th, u16* __restrict__ W2Tl,
                          float* __restrict__ WfT32, float* __restrict__ bias2) {
    int gb = blockIdx.x;
    if (gb < DEGB) {
        int e = gb * 256 + threadIdx.x;
        if (e >= NE) return;
        int t = ei[NE + e];
        atomicAdd(&cnt[t], 1);
        atomicAdd(&ea_sum[t * 2 + 0], ea[e * 2 + 0]);
        atomicAdd(&ea_sum[t * 2 + 1], ea[e * 2 + 1]);
        return;
    }
    int i = (gb - DEGB) * 256 + threadIdx.x;
    if (i < NPA) {
        float a = x[i];
        u16 h = f2bf(a);
        Axh[i] = h;
        Axl[i] = f2bf(a - bf2f(h));
        return;
    }
    i -= NPA;
    if (i < 1024 * 128) {
        int n = i >> 7, k = i & 127;
        float w = (n < 512) ? Wl[k * 512 + n] : Wr[k * 512 + (n - 512)];
        u16 h = f2bf(w);
        W2Th[n * 128 + k] = h;
        W2Tl[n * 128 + k] = f2bf(w - bf2f(h));
    } else if (i < 1024 * 128 + 128 * 128) {
        // fp32 transpose of Wf for the coalesced compose read
        int u = i - 1024 * 128;
        int d = u >> 7, f = u & 127;
        WfT32[u] = Wf[f * 128 + d];
    } else if (i < NPW) {
        int n = i - (1024 * 128 + 128 * 128);
        bias2[n] = (n < 512) ? bl[n] : br[n - 512];
    }
}

// ---------- layer-0 weight composition (R22 math, R24 fast form) ----------
// xl|xr = x@(Wf@W2) + (bf@W2 + b2). R7's slow form: per-lane strided Wf reads
// (VALUBusy 3%) + a 128-long dependent scalar-load chain for the bias.
// Fast form: read WfT32[d*128+f] (lane=f -> coalesced), stage col in LDS once,
// bias via wave-parallel shfl reduction (6 steps, no serial chain).

__global__ __launch_bounds__(256) void k_compose(
        const float* __restrict__ WfT32,
        const float* __restrict__ Wl, const float* __restrict__ Wr,
        const float* __restrict__ bf,
        const float* __restrict__ bl, const float* __restrict__ br,
        u16* __restrict__ WcTh, u16* __restrict__ WcTl,
        float* __restrict__ biasc) {
    __shared__ float scol[2][128];
    int t = threadIdx.x;
    int hn = t >> 7;                    // 0/1: which n of the pair
    int f = t & 127;
    int n = blockIdx.x * 2 + hn;        // 512 blocks x 2 = 1024 outputs
    const float* col = (n < 512) ? &Wl[n] : &Wr[n - 512];
    scol[hn][f] = col[f * 512];         // stage W2 column (128 floats)
    __syncthreads();
    const float* sc = scol[hn];
    float s = 0.f;
    #pragma unroll 8
    for (int d = 0; d < 128; ++d)
        s = fmaf(WfT32[d * 128 + f], sc[d], s);   // same fmaf order as R6
    u16 h = f2bf(s);
    WcTh[n * 128 + f] = h;
    WcTl[n * 128 + f] = f2bf(s - bf2f(h));
    // bias: one wave per n (waves 0 and 2), parallel reduce over d
    if ((t & 64) == 0) {
        int l = t & 63;
        float b = fmaf(bf[l], sc[l], bf[l + 64] * sc[l + 64]);
        b += __shfl_xor(b, 1, 64);
        b += __shfl_xor(b, 2, 64);
        b += __shfl_xor(b, 4, 64);
        b += __shfl_xor(b, 8, 64);
        b += __shfl_xor(b, 16, 64);
        b += __shfl_xor(b, 32, 64);
        if (l == 0)
            biasc[n] = b + ((n < 512) ? bl[n] : br[n - 512]);
    }
}

// ---------- parallel scan (R12/R16-verified pair) ----------

__global__ __launch_bounds__(512) void k_scan_a(const int* __restrict__ cnt,
                                                int* __restrict__ rowptr,
                                                int* __restrict__ bsum) {
    __shared__ int ws[8];
    int tid = threadIdx.x;
    int i = blockIdx.x * 512 + tid;
    int l = tid & 63, w = tid >> 6;
    int v = (i < NN) ? (cnt[i] + 1) : 0;
    #pragma unroll
    for (int off = 1; off < 64; off <<= 1) {
        int u = __shfl_up(v, off, 64);
        if (l >= off) v += u;
    }
    if (l == 63) ws[w] = v;
    __syncthreads();
    if (w == 0) {
        int s = (l < 8) ? ws[l] : 0;
        #pragma unroll
        for (int off = 1; off < 8; off <<= 1) {
            int u = __shfl_up(s, off, 64);
            if (l >= off) s += u;
        }
        if (l < 8) ws[l] = s;    // inclusive wave sums
    }
    __syncthreads();
    v += (w > 0) ? ws[w - 1] : 0;
    if (i < NN) rowptr[i + 1] = v;   // block-local inclusive
    if (tid == 511) bsum[blockIdx.x] = v;
}

__global__ void k_scan_c(int* __restrict__ rowptr, const int* __restrict__ bsum) {
    int l = threadIdx.x & 63;
    int v = (l < NBLK) ? bsum[l] : 0;
    #pragma unroll
    for (int off = 1; off < 64; off <<= 1) {
        int u = __shfl_up(v, off, 64);
        if (l >= off) v += u;
    }
    int i = blockIdx.x * blockDim.x + threadIdx.x;
    int j = i >> 9;
    int off = (j > 0) ? __shfl(v, j - 1, 64) : 0;
    if (i < NN) rowptr[i + 1] += off;
    if (i == 0) rowptr[0] = 0;
}

// ---------- fused fill + self-loop ----------

__global__ void k_fill(const int* __restrict__ ei, const float* __restrict__ ea,
                       const int* __restrict__ rowptr, int* __restrict__ fillc,
                       const int* __restrict__ cnt, const float* __restrict__ ea_sum,
                       int* __restrict__ srcs,
                       float* __restrict__ fa0, float* __restrict__ fa1) {
    int e = blockIdx.x * blockDim.x + threadIdx.x;
    if (e < NE) {
        int s = ei[e], t = ei[NE + e];
        int pos = atomicAdd(&fillc[t], 1);
        int slot = rowptr[t] + pos;
        srcs[slot] = s;
        fa0[slot] = ea[e * 2];
        fa1[slot] = ea[e * 2 + 1];
    } else if (e < NE + NN) {
        int n = e - NE;
        int slot = rowptr[n + 1] - 1;   // self-loop is last slot
        srcs[slot] = n;
        float c = fmaxf((float)cnt[n], 1.f);
        fa0[slot] = ea_sum[n * 2 + 0] / c;
        fa1[slot] = ea_sum[n * 2 + 1] / c;
    }
}

// ---------- split-bf16 MFMA GEMM (R2/R6-exact, best measured config) ----------
// R24: R7's 8-wave variant + fusion regressed 31us with two confounded
// variables -> revert to the structure proven fastest across R0/R1/R2/R6.
// XOR-swizzled LDS (48 KB -> 3 blocks/CU), A-hi staged once via gld16 with
// pre-swizzled global source, A-lo in registers, B gld16 per band, NB=8 bands.

template<int NB>
__global__ __launch_bounds__(256, 3) void k_mgemm(
        const u16* __restrict__ Ahg, const u16* __restrict__ Alg,
        const u16* __restrict__ BTh, const u16* __restrict__ BTl,
        const float* __restrict__ bias, float* __restrict__ C1,
        u16* __restrict__ C2b, int M) {
    __shared__ u16 sAh[64 * 128], sBh[64 * 128], sBl[64 * 128];
    int m0 = blockIdx.y * 64;
    int t = threadIdx.x;
    int lane = t & 63;
    int wm = (t >> 6) & 1;
    int wn = t >> 7;
    int fm = lane & 15;
    int q8 = (lane >> 4) * 8;

    // preload A-lo fragments into registers (8 x 16B per lane).
    short8 fal[4][2];
    #pragma unroll
    for (int i = 0; i < 2; ++i) {
        const u16* p = Alg + (size_t)(m0 + wm * 32 + i * 16 + fm) * 128 + q8;
        #pragma unroll
        for (int kk = 0; kk < 4; ++kk)
            fal[kk][i] = *(const short8*)(p + kk * 32);
    }

    // stage A-hi once via global_load_lds: linear LDS chunk = lane slot,
    // global source pre-swizzled (chunk ch' holds logical chunk ch'^(row&15)).
    #pragma unroll
    for (int i = 0; i < 4; ++i) {
        int cb = (t & 192) + 256 * i;   // wave-uniform chunk base
        int c = cb + lane;
        int row = c >> 4, ch = c & 15;
        int gm = m0 + row;
        if (gm >= M) gm = M - 1;        // clamp: OOB rows finite, never stored
        gld16(&Ahg[(size_t)gm * 128 + ((ch ^ (row & 15)) << 3)], &sAh[cb * 8]);
    }

    int cq = q8 >> 3;   // quarter (0..3)

    for (int bb = 0; bb < NB; ++bb) {
        int n0 = (blockIdx.x * NB + bb) * 64;
        __syncthreads();   // protect sBh/sBl overwrite (covers sAh on bb=0)
        #pragma unroll
        for (int i = 0; i < 4; ++i) {
            int cb = (t & 192) + 256 * i;
            int c = cb + lane;
            int row = c >> 4, ch = c & 15;
            size_t gofs = (size_t)(n0 + row) * 128 + ((ch ^ (row & 15)) << 3);
            gld16(&BTh[gofs], &sBh[cb * 8]);
            gld16(&BTl[gofs], &sBl[cb * 8]);
        }
        __syncthreads();   // vmcnt(0) drained by compiler before barrier

        float4v zz = {0.f, 0.f, 0.f, 0.f};
        float4v acc[2][2];
        acc[0][0] = zz; acc[0][1] = zz; acc[1][0] = zz; acc[1][1] = zz;

        #pragma unroll
        for (int k0 = 0; k0 < 128; k0 += 32) {
            int cl = (k0 >> 3) + cq;        // logical chunk
            int sw = (cl ^ fm) << 3;        // swizzled chunk offset
            short8 fah[2], fbh[2], fbl[2];
            #pragma unroll
            for (int i = 0; i < 2; ++i) {
                int mr = wm * 32 + i * 16 + fm;
                fah[i] = *(const short8*)&sAh[mr * 128 + sw];
                int nr = wn * 32 + i * 16 + fm;
                fbh[i] = *(const short8*)&sBh[nr * 128 + sw];
                fbl[i] = *(const short8*)&sBl[nr * 128 + sw];
            }
            #pragma unroll
            for (int i = 0; i < 2; ++i)
                #pragma unroll
                for (int j = 0; j < 2; ++j) {
                    acc[i][j] = __builtin_amdgcn_mfma_f32_16x16x32_bf16(fah[i], fbh[j], acc[i][j], 0, 0, 0);
                    acc[i][j] = __builtin_amdgcn_mfma_f32_16x16x32_bf16(fah[i], fbl[j], acc[i][j], 0, 0, 0);
                    acc[i][j] = __builtin_amdgcn_mfma_f32_16x16x32_bf16(fal[k0 >> 5][i], fbh[j], acc[i][j], 0, 0, 0);
                }
        }

        // epilogue: C/D layout col=lane&15, row=(lane>>4)*4+reg  [m89]
        #pragma unroll
        for (int i = 0; i < 2; ++i) {
            #pragma unroll
            for (int j = 0; j < 2; ++j) {
                int gn = n0 + wn * 32 + j * 16 + fm;
                float bv = bias[gn];
                #pragma unroll
                for (int r = 0; r < 4; ++r) {
                    int gm = m0 + wm * 32 + i * 16 + (lane >> 4) * 4 + r;
                    if (gm < M) {
                        float v = acc[i][j][r] + bv;
                        if (n0 < 512) {
                            C1[gm * 512 + gn] = v;               // xl fp32
                        } else {
                            C2b[gm * 512 + gn - 512] = f2bf(v);  // xr bf16
                        }
                    }
                }
            }
        }
    }
}

// ---------- fused per-node GATv2: one node per 128-thread block ----------
// R18-R23: k_gat is at the scattered-fill BW floor (FETCH pinned ~180 MB @
// ~3.6 TB/s L2-fill; VALU ~38%; unroll-4 probe moved <2%). Unchanged.

__global__ __launch_bounds__(128) void k_gat(
        const int* __restrict__ rowptr, const int* __restrict__ srcs,
        const float* __restrict__ fa0, const float* __restrict__ fa1,
        const float* __restrict__ xl, const u16* __restrict__ xr,
        const float* __restrict__ We, const float* __restrict__ att,
        const float* __restrict__ bias_out,
        u16* __restrict__ Oh, u16* __restrict__ Ol,
        float* __restrict__ outp, int last) {
    __shared__ float sacc[512];
    __shared__ float sden[4];
    int half = threadIdx.x >> 6;     // 0: even edges + epilogue, 1: odd edges
    int n = blockIdx.x;
    int l = threadIdx.x & 63;
    int d0 = l * 8;

    // per-node constants as packed pairs
    f32x2 xr2[4], we0p[4], we1p[4], at6p[4], at4p[4];
    {
        ushort8 u = *reinterpret_cast<const ushort8*>(&xr[(size_t)n * 512 + d0]);
        #pragma unroll
        for (int k = 0; k < 4; ++k) {
            f32x2 t; t.x = bf2f(u[2 * k]); t.y = bf2f(u[2 * k + 1]);
            xr2[k] = t;
        }
        const f32x2* w0 = reinterpret_cast<const f32x2*>(&We[d0]);
        const f32x2* w1 = reinterpret_cast<const f32x2*>(&We[512 + d0]);
        const f32x2* av = reinterpret_cast<const f32x2*>(&att[d0]);
        #pragma unroll
        for (int k = 0; k < 4; ++k) {
            we0p[k] = w0[k];
            we1p[k] = w1[k];
            f32x2 a = av[k];
            at6p[k] = a * 0.6f;
            at4p[k] = a * 0.4f;
        }
    }

    int b0 = rowptr[n], b1 = rowptr[n + 1];
    int nit = (b1 - b0 - half + 1) >> 1;   // edges of my parity (deg>=1 always)

    // preload my half's edge metadata: lane l owns edge b0 + half + 2*l
    int sv = 0, f0i = 0, f1i = 0;
    {
        int me = b0 + half + 2 * l;
        if (l < nit) {
            sv  = srcs[me];
            f0i = __builtin_bit_cast(int, fa0[me]);
            f1i = __builtin_bit_cast(int, fa1[me]);
        }
    }

    f32x2 acc2[4];
    acc2[0] = f32x2{0.f, 0.f}; acc2[1] = f32x2{0.f, 0.f};
    acc2[2] = f32x2{0.f, 0.f}; acc2[3] = f32x2{0.f, 0.f};
    float den = 0.f;

    auto body = [&](float4 A, float4 B, float f0, float f1) {
        f32x2 f0p; f0p.x = f0; f0p.y = f0;
        f32x2 f1p; f1p.x = f1; f1p.y = f1;
        f32x2 xv2[4];
        xv2[0].x = A.x; xv2[0].y = A.y;
        xv2[1].x = A.z; xv2[1].y = A.w;
        xv2[2].x = B.x; xv2[2].y = B.y;
        xv2[3].x = B.z; xv2[3].y = B.w;
        f32x2 p2 = {0.f, 0.f};
        #pragma unroll
        for (int k = 0; k < 4; ++k) {
            f32x2 t = __builtin_elementwise_fma(f0p, we0p[k], xr2[k]);
            t = __builtin_elementwise_fma(f1p, we1p[k], t);
            f32x2 v2 = xv2[k] + t;
            f32x2 a2 = __builtin_elementwise_abs(v2);
            p2 = __builtin_elementwise_fma(at6p[k], v2, p2);
            p2 = __builtin_elementwise_fma(at4p[k], a2, p2);
        }
        float p = p2.x + p2.y;
        p = dpp_add<0xB1>(p);    // quad_perm xor1
        p = dpp_add<0x4E>(p);    // quad_perm xor2
        p = dpp_add<0x124>(p);   // row_ror:4
        p = dpp_add<0x128>(p);   // row_ror:8 -> full 16-lane (per-head) sum
        float wt = __expf(p);    // |p| small by construction
        den += wt;
        f32x2 wtp; wtp.x = wt; wtp.y = wt;
        #pragma unroll
        for (int k = 0; k < 4; ++k)
            acc2[k] = __builtin_elementwise_fma(wtp, xv2[k], acc2[k]);
    };

    int nfast = nit < 64 ? nit : 64;
    #pragma unroll 4
    for (int it = 0; it < nfast; ++it) {
        int   s  = __builtin_amdgcn_readlane(sv, it);
        float f0 = __builtin_bit_cast(float, __builtin_amdgcn_readlane(f0i, it));
        float f1 = __builtin_bit_cast(float, __builtin_amdgcn_readlane(f1i, it));
        const float* xp = &xl[(size_t)s * 512 + d0];
        float4 A = *reinterpret_cast<const float4*>(xp);
        float4 B = *reinterpret_cast<const float4*>(xp + 4);
        body(A, B, f0, f1);
    }
    // safety tail for deg > 129 (unreachable for this input distribution)
    for (int e = b0 + half + 128; e < b1; e += 2) {
        int s = srcs[e];
        const float* xp = &xl[(size_t)s * 512 + d0];
        float4 A = *reinterpret_cast<const float4*>(xp);
        float4 B = *reinterpret_cast<const float4*>(xp + 4);
        body(A, B, fa0[e], fa1[e]);
    }

    // pair merge: odd wave publishes, even wave combines
    if (half == 1) {
        *reinterpret_cast<float4*>(&sacc[d0]) =
            make_float4(acc2[0].x, acc2[0].y, acc2[1].x, acc2[1].y);
        *reinterpret_cast<float4*>(&sacc[d0 + 4]) =
            make_float4(acc2[2].x, acc2[2].y, acc2[3].x, acc2[3].y);
        if ((l & 15) == 0) sden[l >> 4] = den;
    }
    __syncthreads();
    if (half == 1) return;
    float acc[8] = {acc2[0].x, acc2[0].y, acc2[1].x, acc2[1].y,
                    acc2[2].x, acc2[2].y, acc2[3].x, acc2[3].y};
    #pragma unroll
    for (int k = 0; k < 8; ++k) acc[k] += sacc[d0 + k];
    den += sden[l >> 4];
    // per-head normalize (den identical across the 16 lanes of a head)
    float inv = 1.f / den;
    float val[8];
    #pragma unroll
    for (int k = 0; k < 8; ++k) {
        float v = acc[k] * inv;
        v += __shfl_xor(v, 16, 64);   // sum heads
        v += __shfl_xor(v, 32, 64);
        val[k] = v;
    }
    if (l < 16) {
        #pragma unroll
        for (int k = 0; k < 8; ++k) {
            float v = val[k] * 0.25f + bias_out[d0 + k];
            v = v > 0.f ? v : 0.01f * v;
            val[k] = v;
        }
        if (last) {
            #pragma unroll
            for (int k = 0; k < 8; ++k) outp[n * 128 + d0 + k] = val[k];
        } else {
            #pragma unroll
            for (int k = 0; k < 8; ++k) {
                u16 hv = f2bf(val[k]);
                Oh[n * 128 + d0 + k] = hv;
                Ol[n * 128 + d0 + k] = f2bf(val[k] - bf2f(hv));
            }
        }
    }
}

// ---------- launch ----------

extern "C" void kernel_launch(void* const* d_in, const int* in_sizes, int n_in,
                              void* d_out, int out_size, void* d_ws, size_t ws_size,
                              hipStream_t stream) {
    size_t o = 0;
    auto alloc = [&](size_t bytes) { size_t cur = o; o += (bytes + 255) & ~(size_t)255; return cur; };
    size_t off_cnt    = alloc((size_t)NN * 4);
    size_t off_fillc  = alloc((size_t)NN * 4);
    size_t off_easum  = alloc((size_t)NN * 2 * 4);
    size_t off_rowptr = alloc((size_t)(NN + 1) * 4);
    size_t off_bsum   = alloc((size_t)NBLK * 4);
    size_t off_srcs   = alloc((size_t)EF * 4);
    size_t off_fa0    = alloc((size_t)EF * 4);
    size_t off_fa1    = alloc((size_t)EF * 4);
    size_t off_axh    = alloc((size_t)NN * DD * 2);
    size_t off_axl    = alloc((size_t)NN * DD * 2);
    size_t off_ah     = alloc((size_t)NN * DD * 2);
    size_t off_al     = alloc((size_t)NN * DD * 2);
    size_t off_xl     = alloc((size_t)NN * 512 * 4);
    size_t off_xr     = alloc((size_t)NN * 512 * 2);   // bf16
    size_t off_w2th   = alloc((size_t)1024 * 128 * 2);
    size_t off_w2tl   = alloc((size_t)1024 * 128 * 2);
    size_t off_wcth   = alloc((size_t)1024 * 128 * 2);
    size_t off_wctl   = alloc((size_t)1024 * 128 * 2);
    size_t off_wft32  = alloc((size_t)128 * 128 * 4);
    size_t off_bias2  = alloc((size_t)1024 * 4);
    size_t off_biasc  = alloc((size_t)1024 * 4);
    size_t need = o;

    bool ok = (n_in == 12) && d_ws != nullptr && ws_size >= need
           && out_size == NN * DD
           && in_sizes[0] == NN * DD && in_sizes[1] == 2 * NE
           && in_sizes[2] == NE * 2 && in_sizes[3] == 128 * 128
           && in_sizes[5] == 128 * 512 && in_sizes[9] == 2 * 512
           && in_sizes[10] == 4 * 128 && in_sizes[11] == 128;
    if (!ok) {
        k_zero_f<<<(NN * DD + 255) / 256, 256, 0, stream>>>((float*)d_out, NN * DD);
        return;
    }

    const float* x        = (const float*)d_in[0];
    const int*   ei       = (const int*)d_in[1];
    const float* ea       = (const float*)d_in[2];
    const float* Wf       = (const float*)d_in[3];
    const float* bf       = (const float*)d_in[4];
    const float* Wl       = (const float*)d_in[5];
    const float* bl       = (const float*)d_in[6];
    const float* Wr       = (const float*)d_in[7];
    const float* br       = (const float*)d_in[8];
    const float* We       = (const float*)d_in[9];
    const float* att      = (const float*)d_in[10];
    const float* bias_out = (const float*)d_in[11];

    char* base = (char*)d_ws;
    int*   cnt    = (int*)(base + off_cnt);
    int*   fillc  = (int*)(base + off_fillc);
    float* ea_sum = (float*)(base + off_easum);
    int*   rowptr = (int*)(base + off_rowptr);
    int*   bsum   = (int*)(base + off_bsum);
    int*   srcs   = (int*)(base + off_srcs);
    float* fa0    = (float*)(base + off_fa0);
    float* fa1    = (float*)(base + off_fa1);
    u16*   Axh    = (u16*)(base + off_axh);
    u16*   Axl    = (u16*)(base + off_axl);
    u16*   Ah     = (u16*)(base + off_ah);
    u16*   Al     = (u16*)(base + off_al);
    float* xl     = (float*)(base + off_xl);
    u16*   xr     = (u16*)(base + off_xr);
    u16*   W2Th   = (u16*)(base + off_w2th);
    u16*   W2Tl   = (u16*)(base + off_w2tl);
    u16*   WcTh   = (u16*)(base + off_wcth);
    u16*   WcTl   = (u16*)(base + off_wctl);
    float* WfT32  = (float*)(base + off_wft32);
    float* bias2  = (float*)(base + off_bias2);
    float* biasc  = (float*)(base + off_biasc);

    // zero cnt/fillc/ea_sum (contiguous region) without a kernel launch
    size_t zero_bytes = off_easum + (size_t)NN * 2 * 4 - off_cnt;
    hipMemsetAsync(cnt, 0, zero_bytes, stream);

    k_degpack<<<DEGB + PACKB, 256, 0, stream>>>(ei, ea, x, Wl, Wr, bl, br, Wf,
                                                cnt, ea_sum, Axh, Axl,
                                                W2Th, W2Tl, WfT32, bias2);
    k_compose<<<512, 256, 0, stream>>>(WfT32, Wl, Wr, bf, bl, br,
                                       WcTh, WcTl, biasc);
    k_scan_a<<<NBLK, 512, 0, stream>>>(cnt, rowptr, bsum);
    k_scan_c<<<(NN + 255) / 256, 256, 0, stream>>>(rowptr, bsum);
    k_fill<<<(NE + NN + 255) / 256, 256, 0, stream>>>(ei, ea, rowptr, fillc,
                                                      cnt, ea_sum, srcs, fa0, fa1);

    const int MT = (NN + 63) / 64;   // 313
    for (int layer = 0; layer < 3; ++layer) {
        const u16*   Ahp = (layer == 0) ? Axh  : Ah;
        const u16*   Alp = (layer == 0) ? Axl  : Al;
        const u16*   Bhp = (layer == 0) ? WcTh : W2Th;
        const u16*   Blp = (layer == 0) ? WcTl : W2Tl;
        const float* bp  = (layer == 0) ? biasc : bias2;
        k_mgemm<8><<<dim3(2, MT), 256, 0, stream>>>(Ahp, Alp, Bhp, Blp,
                                                    bp, xl, xr, NN);
        int last = (layer == 2);
        k_gat<<<NN, 128, 0, stream>>>(rowptr, srcs, fa0, fa1, xl, xr,
                                      We, att, bias_out, Ah, Al,
                                      (float*)d_out, last);
    }
}